// Round 8
// baseline (164.468 us; speedup 1.0000x reference)
//
#include <hip/hip_runtime.h>
#include <math.h>

#define HW 2304           // 48*48
#define O192 192
#define SCALE_F 0.35355339059327373f   // 8^-0.5

typedef unsigned int u32;
typedef __attribute__((address_space(1))) const u32 gu32;
typedef __attribute__((address_space(3))) u32 lu32;
// async global->LDS DMA, 16B per lane; LDS dest = wave-uniform base + lane*16
__device__ __forceinline__ void dma16(const void* g, void* l) {
  __builtin_amdgcn_global_load_lds((gu32*)g, (lu32*)l, 16, 0, 0);
}

// ---------------- Kernel A: 1x1 conv -> q,k (QKV) and v (V2) ----------------
__global__ __launch_bounds__(256) void qkv_kernel(
    const float* __restrict__ F, const float* __restrict__ W,
    float* __restrict__ QKV, float* __restrict__ V2) {
  __shared__ __align__(16) float sW[384];   // two o0 sets x {q,k,v} rows x 64
  int blk = blockIdx.x;
  int idx0 = blk * 256;
  int r0 = idx0 / HW;
  int r1 = (idx0 + 255) / HW;
  int tid = threadIdx.x;
  if (tid < 192) {
    int g = tid >> 6, c = tid & 63;
    sW[tid]       = W[((r0 & 63) + g * 64) * 64 + c];
    sW[192 + tid] = W[((r1 & 63) + g * 64) * 64 + c];
  }
  __syncthreads();
  int idx = idx0 + tid;
  int p  = idx % HW;
  int r  = idx / HW;
  int o0 = r & 63;
  int b  = r >> 6;
  const float4* w4 = (const float4*)(sW + ((r == r0) ? 0 : 192));
  const float* f = F + (b * 64) * HW + p;
  float aq = 0.f, ak = 0.f, av = 0.f;
  #pragma unroll 4
  for (int c4 = 0; c4 < 16; c4++) {
    float4 wq = w4[c4];
    float4 wk = w4[16 + c4];
    float4 wv = w4[32 + c4];
    float f0 = f[(c4 * 4 + 0) * HW];
    float f1 = f[(c4 * 4 + 1) * HW];
    float f2 = f[(c4 * 4 + 2) * HW];
    float f3 = f[(c4 * 4 + 3) * HW];
    aq = fmaf(wq.x, f0, aq); ak = fmaf(wk.x, f0, ak); av = fmaf(wv.x, f0, av);
    aq = fmaf(wq.y, f1, aq); ak = fmaf(wk.y, f1, ak); av = fmaf(wv.y, f1, av);
    aq = fmaf(wq.z, f2, aq); ak = fmaf(wk.z, f2, ak); av = fmaf(wv.z, f2, av);
    aq = fmaf(wq.w, f3, aq); ak = fmaf(wk.w, f3, ak); av = fmaf(wv.w, f3, av);
  }
  float* qp = QKV + (b * HW + p) * O192;
  qp[o0]      = aq;
  qp[o0 + 64] = ak;
  V2[(((b << 3) + (o0 >> 3)) * HW + p) * 8 + (o0 & 7)] = av;
}

// ---------------- Kernel B: 11x11 stride-8 conv + bias + exact GELU ----------
__global__ __launch_bounds__(256) void conv_kernel(
    const float* __restrict__ QKV, const float* __restrict__ Wq,
    const float* __restrict__ Bq, const float* __restrict__ Wk,
    const float* __restrict__ Bk, float* __restrict__ QD) {
  __shared__ float sW[7744];
  __shared__ float sRed[4 * 64 * 6];
  int blk = blockIdx.x;
  int xcd = blk & 7;
  int T = xcd >> 2, b = (xcd >> 1) & 1, s = xcd & 1;
  int idx = (blk >> 3) * 2 + s;
  int o  = idx / 6;
  int oy = idx % 6;
  const float* Wg = T ? Wk : Wq;
  for (int i = threadIdx.x; i < 7744; i += 256) sW[i] = Wg[o * 7744 + i];
  __syncthreads();
  int wv = threadIdx.x >> 6;
  int c  = threadIdx.x & 63;
  const float* base = QKV + b * (HW * O192) + T * 64 + c;
  float acc[6];
  #pragma unroll
  for (int ox = 0; ox < 6; ox++) acc[ox] = 0.f;
  for (int kyi = 0; kyi < 3; kyi++) {
    int ky = wv * 3 + kyi;
    if (ky > 10) break;
    int y = oy * 8 - 2 + ky;
    if ((unsigned)y < 48u) {
      float xrow[48];
      #pragma unroll
      for (int x = 0; x < 48; x++) xrow[x] = base[(y * 48 + x) * O192];
      #pragma unroll
      for (int kx = 0; kx < 11; kx++) {
        float wt = sW[c * 121 + ky * 11 + kx];
        #pragma unroll
        for (int ox = 0; ox < 6; ox++) {
          int x = ox * 8 - 2 + kx;
          if (x >= 0 && x < 48) acc[ox] = fmaf(xrow[x], wt, acc[ox]);
        }
      }
    }
  }
  #pragma unroll
  for (int ox = 0; ox < 6; ox++) sRed[(wv * 64 + c) * 6 + ox] = acc[ox];
  __syncthreads();
  if (threadIdx.x < 64) {
    int t = threadIdx.x;
    float r[6];
    #pragma unroll
    for (int ox = 0; ox < 6; ox++)
      r[ox] = sRed[t * 6 + ox] + sRed[(64 + t) * 6 + ox]
            + sRed[(128 + t) * 6 + ox] + sRed[(192 + t) * 6 + ox];
    #pragma unroll
    for (int off = 32; off; off >>= 1) {
      #pragma unroll
      for (int ox = 0; ox < 6; ox++) r[ox] += __shfl_down(r[ox], off, 64);
    }
    if (t == 0) {
      float bias = T ? Bk[o] : Bq[o];
      #pragma unroll
      for (int ox = 0; ox < 6; ox++) {
        float g = r[ox] + bias;
        float ge = 0.5f * g * (1.0f + erff(g * 0.70710678118654752f));
        QD[((T * 2 + b) * 64 + o) * 36 + oy * 6 + ox] = ge;
      }
    }
  }
}

// ---------------- Kernel C: full-j attention (r7 shell, 2 rows/lane) --------
// Lessons: no device fences (r1); V LDS-staged via dma16 (r4); no VGPR cap
// from launch_bounds (r2/r5/r6 spill). r7 PMC showed the kernel is
// LDS-ISSUE-bound (12 broadcast ds_read_b128/wave/jy ~= 35us of LDS pipe;
// VALU ~14us hides under it). This round: 2 rows/lane halves LDS ops per fma:
//  * 16 jx-groups x 3 jx, group = quarter-wave (16 lanes); lane owns rows
//    {rl16, rl16+16}. V addrs: 4 distinct 16B lines/wave at 96B spacing ->
//    bank starts {0,24,16,8}: conflict-free.
//  * eA stored as interleaved row-pairs -> one ds_read_b64 serves both rows.
//  * main loop: 6 b128 + 1 b64 per wave per jy (was 12 b128 + 1 b32).
// Shell (grid 1152x256, 32 rows, DMA quarters, barrier cadence, E, QT,
// epilogue LDS size) byte-identical to r7.
#define OFF_V   0        // 4608 f : V quarter [12jy][48jx][8c]
#define OFF_EA  4608     // 384  f : eA2 [jyL][r16][2] (row r16, row r16+16)
#define OFF_PHT 4992     // 384  f : PH^T [jy][c]
#define OFF_PWT 5376     // 384  f : PW^T [jx][c]
#define OFF_E   5760     // 36+4 f : E [J]
#define OFF_QT  5800     // 256  f : sQT [c][row]  (transposed)
#define OFF_R   6056     // 1152 f : sRed [4w][2k][16 r16][9]
#define SBUF_N  7208     // 28832 B -> 5 blocks/CU

__global__ __launch_bounds__(256) void attn_kernel(
    const float* __restrict__ QKV, const float* __restrict__ V2,
    const float* __restrict__ QD, const float* __restrict__ PH,
    const float* __restrict__ PW, float* __restrict__ out) {
  __shared__ __align__(16) float sB[SBUF_N];
  int blk = blockIdx.x;
  int bh = blk / 72;
  int S  = blk - bh * 72;         // 32-row supertile; I column = S>>1
  int b = bh >> 3, h = bh & 7;
  int tid = threadIdx.x;
  int w = tid >> 6, lane = tid & 63;   // 4 waves
  int rl16 = lane & 15;                // first owned row; second is rl16+16
  int g  = w * 4 + (lane >> 4);        // jx-group in [0,16), 3 jx each
  // ---- stage tables (256 threads -> strided over 384) ----
  for (int t = tid; t < 384; t += 256) {
    sB[OFF_PHT + t] = PH[(t & 7) * 48 + (t >> 3)];
    sB[OFF_PWT + t] = PW[(t & 7) * 48 + (t >> 3)];
  }
  if (tid < 36) {   // fused dots: E[J] = exp(SCALE * qd[:,I].kd[:,J])
    int I = S >> 1;
    float acc = 0.f;
    #pragma unroll
    for (int c8 = 0; c8 < 8; c8++) {
      float qv = QD[((0 + b) * 64 + h * 8 + c8) * 36 + I];
      float kv = QD[((2 + b) * 64 + h * 8 + c8) * 36 + tid];
      acc = fmaf(qv, kv, acc);
    }
    sB[OFF_E + tid] = __expf(SCALE_F * acc);
  }
  {  // sQT[c][row] transposed: 256 threads = 32 rows x 8 c
    int row = tid >> 3, c = tid & 7;
    sB[OFF_QT + c * 32 + row] =
      QKV[(b * HW + S * 32 + row) * O192 + h * 8 + c];
  }
  { // V quarter 0 via DMA: 18 chunks x 1 KiB over 4 waves
    const char* src = (const char*)(V2 + (size_t)bh * (HW * 8));
    for (int m = w; m < 18; m += 4)
      dma16(src + m * 1024 + lane * 16, (char*)(sB + OFF_V) + m * 1024);
  }
  __syncthreads();   // publish tables/QT; drains V(0) DMA
  // ---- eB regs: 2 rows x 3 jx ----
  float eB[2][3];
  #pragma unroll
  for (int k = 0; k < 2; k++) {
    int row = rl16 + k * 16;
    #pragma unroll
    for (int i = 0; i < 3; i++) {
      const float* pp = sB + OFF_PWT + (g * 3 + i) * 8;
      float d = 0.f;
      #pragma unroll
      for (int j = 0; j < 8; j++) d = fmaf(sB[OFF_QT + j * 32 + row], pp[j], d);
      eB[k][i] = __expf(d);
    }
  }
  // ---- main: 4 quarters x 12 jy; V broadcast from LDS ----
  float acc0[9], acc1[9];
  #pragma unroll
  for (int c = 0; c < 9; c++) { acc0[c] = 0.f; acc1[c] = 0.f; }
  const float4* sV4 = (const float4*)(sB + OFF_V);
  for (int q = 0; q < 4; q++) {
    // eA2(q): exp(q_row . PH[:, q*12+jyL]) interleaved [jyL][r16][k]
    for (int t = tid; t < 384; t += 256) {
      int jyL = t >> 5, rr = t & 31;
      const float* pp = sB + OFF_PHT + (q * 12 + jyL) * 8;
      float d = 0.f;
      #pragma unroll
      for (int j = 0; j < 8; j++) d = fmaf(sB[OFF_QT + j * 32 + rr], pp[j], d);
      sB[OFF_EA + jyL * 32 + ((rr & 15) << 1) + (rr >> 4)] = __expf(d);
    }
    __syncthreads();   // publish eA(q); drains V(q) DMA (for q>0)
    for (int jyL = 0; jyL < 12; jyL++) {
      float2 eA = *(const float2*)(sB + OFF_EA + jyL * 32 + rl16 * 2);
      int cb = (q * 12 + jyL) * 48 + g * 3;     // global j of i=0
      int J0 = cb >> 6, J1 = (cb + 2) >> 6;
      int ib = 64 - (cb & 63);                  // i >= ib uses J1
      float e0 = sB[OFF_E + J0];
      float e1 = sB[OFF_E + J1];
      float a00 = eA.x * e0, a01 = eA.x * e1;
      float a10 = eA.y * e0, a11 = eA.y * e1;
      #pragma unroll
      for (int i = 0; i < 3; i++) {
        float4 vlo = sV4[(jyL * 48 + g * 3 + i) * 2];
        float4 vhi = sV4[(jyL * 48 + g * 3 + i) * 2 + 1];
        bool sel = (i < ib);
        float w0 = (sel ? a00 : a01) * eB[0][i];
        float w1 = (sel ? a10 : a11) * eB[1][i];
        acc0[0] = fmaf(w0, vlo.x, acc0[0]);  acc1[0] = fmaf(w1, vlo.x, acc1[0]);
        acc0[1] = fmaf(w0, vlo.y, acc0[1]);  acc1[1] = fmaf(w1, vlo.y, acc1[1]);
        acc0[2] = fmaf(w0, vlo.z, acc0[2]);  acc1[2] = fmaf(w1, vlo.z, acc1[2]);
        acc0[3] = fmaf(w0, vlo.w, acc0[3]);  acc1[3] = fmaf(w1, vlo.w, acc1[3]);
        acc0[4] = fmaf(w0, vhi.x, acc0[4]);  acc1[4] = fmaf(w1, vhi.x, acc1[4]);
        acc0[5] = fmaf(w0, vhi.y, acc0[5]);  acc1[5] = fmaf(w1, vhi.y, acc1[5]);
        acc0[6] = fmaf(w0, vhi.z, acc0[6]);  acc1[6] = fmaf(w1, vhi.z, acc1[6]);
        acc0[7] = fmaf(w0, vhi.w, acc0[7]);  acc1[7] = fmaf(w1, vhi.w, acc1[7]);
        acc0[8] += w0;                        acc1[8] += w1;
      }
    }
    if (q < 3) {
      __syncthreads();   // all waves done reading V(q)/eA(q)
      const char* src = (const char*)(V2 + (size_t)bh * (HW * 8) + (size_t)(q + 1) * 4608);
      for (int m = w; m < 18; m += 4)
        dma16(src + m * 1024 + lane * 16, (char*)(sB + OFF_V) + m * 1024);
      // latency covered by next quarter's eA build; its barrier drains DMA
    }
  }
  // ---- reduce: sum the wave's 4 jx-groups in-register, then 4 waves -------
  #pragma unroll
  for (int c = 0; c < 9; c++) {
    acc0[c] += __shfl_xor(acc0[c], 16, 64);
    acc0[c] += __shfl_xor(acc0[c], 32, 64);
    acc1[c] += __shfl_xor(acc1[c], 16, 64);
    acc1[c] += __shfl_xor(acc1[c], 32, 64);
  }
  if ((lane & 48) == 0) {   // lanes 0-15 hold the wave's group-sum
    #pragma unroll
    for (int c = 0; c < 9; c++) {
      sB[OFF_R + ((w * 2 + 0) * 16 + rl16) * 9 + c] = acc0[c];
      sB[OFF_R + ((w * 2 + 1) * 16 + rl16) * 9 + c] = acc1[c];
    }
  }
  __syncthreads();
  {
    int c = tid >> 5, r = tid & 31;   // 256 threads = 32 rows x 8 c
    int k = r >> 4, r16 = r & 15;
    float num = 0.f, z = 0.f;
    #pragma unroll
    for (int ww = 0; ww < 4; ww++) {
      num += sB[OFF_R + ((ww * 2 + k) * 16 + r16) * 9 + c];
      z   += sB[OFF_R + ((ww * 2 + k) * 16 + r16) * 9 + 8];
    }
    out[(b * 64 + h * 8 + c) * HW + S * 32 + r] = num / z;
  }
}

extern "C" void kernel_launch(void* const* d_in, const int* in_sizes, int n_in,
                              void* d_out, int out_size, void* d_ws, size_t ws_size,
                              hipStream_t stream) {
  const float* F    = (const float*)d_in[0];
  const float* Wqkv = (const float*)d_in[1];
  const float* Wq   = (const float*)d_in[2];
  const float* Bq   = (const float*)d_in[3];
  const float* Wk   = (const float*)d_in[4];
  const float* Bk   = (const float*)d_in[5];
  const float* PH   = (const float*)d_in[6];
  const float* PW   = (const float*)d_in[7];
  float* out = (float*)d_out;

  float* ws   = (float*)d_ws;
  float* QKV  = ws;                        // 884736 f
  float* V2   = QKV + 2 * HW * O192;       // 294912 f
  float* QD   = V2 + 2 * 8 * HW * 8;       // 9216 f   (~4.8 MB total)

  qkv_kernel <<<1152, 256, 0, stream>>>(F, Wqkv, QKV, V2);
  conv_kernel<<<1536, 256, 0, stream>>>(QKV, Wq, Bq, Wk, Bk, QD);
  attn_kernel<<<1152, 256, 0, stream>>>(QKV, V2, QD, PH, PW, out);
}

// Round 9
// 132.453 us; speedup vs baseline: 1.2417x; 1.2417x over previous
//
#include <hip/hip_runtime.h>
#include <math.h>

#define HW 2304           // 48*48
#define O192 192
#define SCALE_F 0.35355339059327373f   // 8^-0.5

typedef unsigned int u32;
typedef __attribute__((address_space(1))) const u32 gu32;
typedef __attribute__((address_space(3))) u32 lu32;
// async global->LDS DMA, 16B per lane; LDS dest = wave-uniform base + lane*16
__device__ __forceinline__ void dma16(const void* g, void* l) {
  __builtin_amdgcn_global_load_lds((gu32*)g, (lu32*)l, 16, 0, 0);
}

// ---------------- Kernel A: 1x1 conv -> q,k (QKV) and v (V2) ----------------
__global__ __launch_bounds__(256) void qkv_kernel(
    const float* __restrict__ F, const float* __restrict__ W,
    float* __restrict__ QKV, float* __restrict__ V2) {
  __shared__ __align__(16) float sW[384];   // two o0 sets x {q,k,v} rows x 64
  int blk = blockIdx.x;
  int idx0 = blk * 256;
  int r0 = idx0 / HW;
  int r1 = (idx0 + 255) / HW;
  int tid = threadIdx.x;
  if (tid < 192) {
    int g = tid >> 6, c = tid & 63;
    sW[tid]       = W[((r0 & 63) + g * 64) * 64 + c];
    sW[192 + tid] = W[((r1 & 63) + g * 64) * 64 + c];
  }
  __syncthreads();
  int idx = idx0 + tid;
  int p  = idx % HW;
  int r  = idx / HW;
  int o0 = r & 63;
  int b  = r >> 6;
  const float4* w4 = (const float4*)(sW + ((r == r0) ? 0 : 192));
  const float* f = F + (b * 64) * HW + p;
  float aq = 0.f, ak = 0.f, av = 0.f;
  #pragma unroll 4
  for (int c4 = 0; c4 < 16; c4++) {
    float4 wq = w4[c4];
    float4 wk = w4[16 + c4];
    float4 wv = w4[32 + c4];
    float f0 = f[(c4 * 4 + 0) * HW];
    float f1 = f[(c4 * 4 + 1) * HW];
    float f2 = f[(c4 * 4 + 2) * HW];
    float f3 = f[(c4 * 4 + 3) * HW];
    aq = fmaf(wq.x, f0, aq); ak = fmaf(wk.x, f0, ak); av = fmaf(wv.x, f0, av);
    aq = fmaf(wq.y, f1, aq); ak = fmaf(wk.y, f1, ak); av = fmaf(wv.y, f1, av);
    aq = fmaf(wq.z, f2, aq); ak = fmaf(wk.z, f2, ak); av = fmaf(wv.z, f2, av);
    aq = fmaf(wq.w, f3, aq); ak = fmaf(wk.w, f3, ak); av = fmaf(wv.w, f3, av);
  }
  float* qp = QKV + (b * HW + p) * O192;
  qp[o0]      = aq;
  qp[o0 + 64] = ak;
  V2[(((b << 3) + (o0 >> 3)) * HW + p) * 8 + (o0 & 7)] = av;
}

// ---------------- Kernel B: 11x11 stride-8 conv + bias + exact GELU ----------
__global__ __launch_bounds__(256) void conv_kernel(
    const float* __restrict__ QKV, const float* __restrict__ Wq,
    const float* __restrict__ Bq, const float* __restrict__ Wk,
    const float* __restrict__ Bk, float* __restrict__ QD) {
  __shared__ float sW[7744];
  __shared__ float sRed[4 * 64 * 6];
  int blk = blockIdx.x;
  int xcd = blk & 7;
  int T = xcd >> 2, b = (xcd >> 1) & 1, s = xcd & 1;
  int idx = (blk >> 3) * 2 + s;
  int o  = idx / 6;
  int oy = idx % 6;
  const float* Wg = T ? Wk : Wq;
  for (int i = threadIdx.x; i < 7744; i += 256) sW[i] = Wg[o * 7744 + i];
  __syncthreads();
  int wv = threadIdx.x >> 6;
  int c  = threadIdx.x & 63;
  const float* base = QKV + b * (HW * O192) + T * 64 + c;
  float acc[6];
  #pragma unroll
  for (int ox = 0; ox < 6; ox++) acc[ox] = 0.f;
  for (int kyi = 0; kyi < 3; kyi++) {
    int ky = wv * 3 + kyi;
    if (ky > 10) break;
    int y = oy * 8 - 2 + ky;
    if ((unsigned)y < 48u) {
      float xrow[48];
      #pragma unroll
      for (int x = 0; x < 48; x++) xrow[x] = base[(y * 48 + x) * O192];
      #pragma unroll
      for (int kx = 0; kx < 11; kx++) {
        float wt = sW[c * 121 + ky * 11 + kx];
        #pragma unroll
        for (int ox = 0; ox < 6; ox++) {
          int x = ox * 8 - 2 + kx;
          if (x >= 0 && x < 48) acc[ox] = fmaf(xrow[x], wt, acc[ox]);
        }
      }
    }
  }
  #pragma unroll
  for (int ox = 0; ox < 6; ox++) sRed[(wv * 64 + c) * 6 + ox] = acc[ox];
  __syncthreads();
  if (threadIdx.x < 64) {
    int t = threadIdx.x;
    float r[6];
    #pragma unroll
    for (int ox = 0; ox < 6; ox++)
      r[ox] = sRed[t * 6 + ox] + sRed[(64 + t) * 6 + ox]
            + sRed[(128 + t) * 6 + ox] + sRed[(192 + t) * 6 + ox];
    #pragma unroll
    for (int off = 32; off; off >>= 1) {
      #pragma unroll
      for (int ox = 0; ox < 6; ox++) r[ox] += __shfl_down(r[ox], off, 64);
    }
    if (t == 0) {
      float bias = T ? Bk[o] : Bq[o];
      #pragma unroll
      for (int ox = 0; ox < 6; ox++) {
        float g = r[ox] + bias;
        float ge = 0.5f * g * (1.0f + erff(g * 0.70710678118654752f));
        QD[((T * 2 + b) * 64 + o) * 36 + oy * 6 + ox] = ge;
      }
    }
  }
}

// ---------------- Kernel C: attention, 2 rows/lane + pinned unrolling -------
// Lessons: no device fences (r1); V LDS-staged via dma16 (r4); no VGPR cap
// (r2/r5/r6: cap<=demand -> spill); AND r8: with a small loop body hipcc
// fully unrolls+pipelines the 12-iter jyL loop -> VGPR 208 -> occupancy 9%.
// Fix: #pragma unroll 1 on the jyL and q loops pins the live set (~18 acc +
// 6 eB + V frags ~= 50-70 VGPR). Structure is r8's (halves LDS issues vs r7:
// 6 b128 + 1 b64 per wave per jy, the r7 PMC-diagnosed LDS-issue bound):
//  * 16 jx-groups x 3 jx, group = quarter-wave; lane owns rows {rl16,rl16+16}
//  * V addrs: 4 distinct 16B lines/wave at 96B spacing -> conflict-free
//  * eA interleaved row-pairs -> one ds_read_b64 serves both rows
#define OFF_V   0        // 4608 f : V quarter [12jy][48jx][8c]
#define OFF_EA  4608     // 384  f : eA2 [jyL][r16][2] (row r16, row r16+16)
#define OFF_PHT 4992     // 384  f : PH^T [jy][c]
#define OFF_PWT 5376     // 384  f : PW^T [jx][c]
#define OFF_E   5760     // 36+4 f : E [J]
#define OFF_QT  5800     // 256  f : sQT [c][row]  (transposed)
#define OFF_R   6056     // 1152 f : sRed [4w][2k][16 r16][9]
#define SBUF_N  7208     // 28832 B -> 5 blocks/CU

__global__ __launch_bounds__(256) void attn_kernel(
    const float* __restrict__ QKV, const float* __restrict__ V2,
    const float* __restrict__ QD, const float* __restrict__ PH,
    const float* __restrict__ PW, float* __restrict__ out) {
  __shared__ __align__(16) float sB[SBUF_N];
  int blk = blockIdx.x;
  int bh = blk / 72;
  int S  = blk - bh * 72;         // 32-row supertile; I column = S>>1
  int b = bh >> 3, h = bh & 7;
  int tid = threadIdx.x;
  int w = tid >> 6, lane = tid & 63;   // 4 waves
  int rl16 = lane & 15;                // first owned row; second is rl16+16
  int g  = w * 4 + (lane >> 4);        // jx-group in [0,16), 3 jx each
  // ---- stage tables (256 threads -> strided over 384) ----
  for (int t = tid; t < 384; t += 256) {
    sB[OFF_PHT + t] = PH[(t & 7) * 48 + (t >> 3)];
    sB[OFF_PWT + t] = PW[(t & 7) * 48 + (t >> 3)];
  }
  if (tid < 36) {   // fused dots: E[J] = exp(SCALE * qd[:,I].kd[:,J])
    int I = S >> 1;
    float acc = 0.f;
    #pragma unroll
    for (int c8 = 0; c8 < 8; c8++) {
      float qv = QD[((0 + b) * 64 + h * 8 + c8) * 36 + I];
      float kv = QD[((2 + b) * 64 + h * 8 + c8) * 36 + tid];
      acc = fmaf(qv, kv, acc);
    }
    sB[OFF_E + tid] = __expf(SCALE_F * acc);
  }
  {  // sQT[c][row] transposed: 256 threads = 32 rows x 8 c
    int row = tid >> 3, c = tid & 7;
    sB[OFF_QT + c * 32 + row] =
      QKV[(b * HW + S * 32 + row) * O192 + h * 8 + c];
  }
  { // V quarter 0 via DMA: 18 chunks x 1 KiB over 4 waves
    const char* src = (const char*)(V2 + (size_t)bh * (HW * 8));
    for (int m = w; m < 18; m += 4)
      dma16(src + m * 1024 + lane * 16, (char*)(sB + OFF_V) + m * 1024);
  }
  __syncthreads();   // publish tables/QT; drains V(0) DMA
  // ---- eB regs: 2 rows x 3 jx ----
  float eB[2][3];
  #pragma unroll
  for (int k = 0; k < 2; k++) {
    int row = rl16 + k * 16;
    #pragma unroll
    for (int i = 0; i < 3; i++) {
      const float* pp = sB + OFF_PWT + (g * 3 + i) * 8;
      float d = 0.f;
      #pragma unroll
      for (int j = 0; j < 8; j++) d = fmaf(sB[OFF_QT + j * 32 + row], pp[j], d);
      eB[k][i] = __expf(d);
    }
  }
  // ---- main: 4 quarters x 12 jy; V broadcast from LDS ----
  float acc0[9], acc1[9];
  #pragma unroll
  for (int c = 0; c < 9; c++) { acc0[c] = 0.f; acc1[c] = 0.f; }
  const float4* sV4 = (const float4*)(sB + OFF_V);
  #pragma unroll 1
  for (int q = 0; q < 4; q++) {
    // eA2(q): exp(q_row . PH[:, q*12+jyL]) interleaved [jyL][r16][k]
    for (int t = tid; t < 384; t += 256) {
      int jyL = t >> 5, rr = t & 31;
      const float* pp = sB + OFF_PHT + (q * 12 + jyL) * 8;
      float d = 0.f;
      #pragma unroll
      for (int j = 0; j < 8; j++) d = fmaf(sB[OFF_QT + j * 32 + rr], pp[j], d);
      sB[OFF_EA + jyL * 32 + ((rr & 15) << 1) + (rr >> 4)] = __expf(d);
    }
    __syncthreads();   // publish eA(q); drains V(q) DMA (for q>0)
    #pragma unroll 1
    for (int jyL = 0; jyL < 12; jyL++) {
      float2 eA = *(const float2*)(sB + OFF_EA + jyL * 32 + rl16 * 2);
      int cb = (q * 12 + jyL) * 48 + g * 3;     // global j of i=0
      int J0 = cb >> 6, J1 = (cb + 2) >> 6;
      int ib = 64 - (cb & 63);                  // i >= ib uses J1
      float e0 = sB[OFF_E + J0];
      float e1 = sB[OFF_E + J1];
      float a00 = eA.x * e0, a01 = eA.x * e1;
      float a10 = eA.y * e0, a11 = eA.y * e1;
      #pragma unroll
      for (int i = 0; i < 3; i++) {
        float4 vlo = sV4[(jyL * 48 + g * 3 + i) * 2];
        float4 vhi = sV4[(jyL * 48 + g * 3 + i) * 2 + 1];
        bool sel = (i < ib);
        float w0 = (sel ? a00 : a01) * eB[0][i];
        float w1 = (sel ? a10 : a11) * eB[1][i];
        acc0[0] = fmaf(w0, vlo.x, acc0[0]);  acc1[0] = fmaf(w1, vlo.x, acc1[0]);
        acc0[1] = fmaf(w0, vlo.y, acc0[1]);  acc1[1] = fmaf(w1, vlo.y, acc1[1]);
        acc0[2] = fmaf(w0, vlo.z, acc0[2]);  acc1[2] = fmaf(w1, vlo.z, acc1[2]);
        acc0[3] = fmaf(w0, vlo.w, acc0[3]);  acc1[3] = fmaf(w1, vlo.w, acc1[3]);
        acc0[4] = fmaf(w0, vhi.x, acc0[4]);  acc1[4] = fmaf(w1, vhi.x, acc1[4]);
        acc0[5] = fmaf(w0, vhi.y, acc0[5]);  acc1[5] = fmaf(w1, vhi.y, acc1[5]);
        acc0[6] = fmaf(w0, vhi.z, acc0[6]);  acc1[6] = fmaf(w1, vhi.z, acc1[6]);
        acc0[7] = fmaf(w0, vhi.w, acc0[7]);  acc1[7] = fmaf(w1, vhi.w, acc1[7]);
        acc0[8] += w0;                        acc1[8] += w1;
      }
    }
    if (q < 3) {
      __syncthreads();   // all waves done reading V(q)/eA(q)
      const char* src = (const char*)(V2 + (size_t)bh * (HW * 8) + (size_t)(q + 1) * 4608);
      for (int m = w; m < 18; m += 4)
        dma16(src + m * 1024 + lane * 16, (char*)(sB + OFF_V) + m * 1024);
      // latency covered by next quarter's eA build; its barrier drains DMA
    }
  }
  // ---- reduce: sum the wave's 4 jx-groups in-register, then 4 waves -------
  #pragma unroll
  for (int c = 0; c < 9; c++) {
    acc0[c] += __shfl_xor(acc0[c], 16, 64);
    acc0[c] += __shfl_xor(acc0[c], 32, 64);
    acc1[c] += __shfl_xor(acc1[c], 16, 64);
    acc1[c] += __shfl_xor(acc1[c], 32, 64);
  }
  if ((lane & 48) == 0) {   // lanes 0-15 hold the wave's group-sum
    #pragma unroll
    for (int c = 0; c < 9; c++) {
      sB[OFF_R + ((w * 2 + 0) * 16 + rl16) * 9 + c] = acc0[c];
      sB[OFF_R + ((w * 2 + 1) * 16 + rl16) * 9 + c] = acc1[c];
    }
  }
  __syncthreads();
  {
    int c = tid >> 5, r = tid & 31;   // 256 threads = 32 rows x 8 c
    int k = r >> 4, r16 = r & 15;
    float num = 0.f, z = 0.f;
    #pragma unroll
    for (int ww = 0; ww < 4; ww++) {
      num += sB[OFF_R + ((ww * 2 + k) * 16 + r16) * 9 + c];
      z   += sB[OFF_R + ((ww * 2 + k) * 16 + r16) * 9 + 8];
    }
    out[(b * 64 + h * 8 + c) * HW + S * 32 + r] = num / z;
  }
}

extern "C" void kernel_launch(void* const* d_in, const int* in_sizes, int n_in,
                              void* d_out, int out_size, void* d_ws, size_t ws_size,
                              hipStream_t stream) {
  const float* F    = (const float*)d_in[0];
  const float* Wqkv = (const float*)d_in[1];
  const float* Wq   = (const float*)d_in[2];
  const float* Bq   = (const float*)d_in[3];
  const float* Wk   = (const float*)d_in[4];
  const float* Bk   = (const float*)d_in[5];
  const float* PH   = (const float*)d_in[6];
  const float* PW   = (const float*)d_in[7];
  float* out = (float*)d_out;

  float* ws   = (float*)d_ws;
  float* QKV  = ws;                        // 884736 f
  float* V2   = QKV + 2 * HW * O192;       // 294912 f
  float* QD   = V2 + 2 * 8 * HW * 8;       // 9216 f   (~4.8 MB total)

  qkv_kernel <<<1152, 256, 0, stream>>>(F, Wqkv, QKV, V2);
  conv_kernel<<<1536, 256, 0, stream>>>(QKV, Wq, Bq, Wk, Bk, QD);
  attn_kernel<<<1152, 256, 0, stream>>>(QKV, V2, QD, PH, PW, out);
}